// Round 20
// baseline (3252.712 us; speedup 1.0000x reference)
//
#include <hip/hip_runtime.h>
#include <hip/hip_bf16.h>
#include <math.h>

#define B_   16
#define S_   1024
#define R_   512
#define H_   512
#define HD_  256
#define G_   1024
#define DIN_ 1536

// ---------------------------------------------------------------------------
// Tiled fp32 GEMM:  C[m][n] = sum_k A(m,k) * B(n,k)   (steps 1 and 2 only)
// ---------------------------------------------------------------------------
template<int EPI, int REMAP_A>
__global__ __launch_bounds__(256) void gemm_mk_nk(
    const float* __restrict__ A, long a_rs, long a_bs,
    const float* __restrict__ Bm, long b_rs, long b_bs,
    float* __restrict__ C, long c_rs, long c_bs,
    const float* __restrict__ bias,
    int M, int N, int K)
{
    __shared__ float As[16][68];
    __shared__ float Bs[16][68];
    const int bb = blockIdx.z;
    const float* Ab = A + (long)bb * a_bs;
    const float* Bb = Bm + (long)bb * b_bs;
    float* Cb = C + (long)bb * c_bs;
    const int m0 = blockIdx.y * 64, n0 = blockIdx.x * 64;
    const int tid = threadIdx.x;
    const int tx = tid & 15, ty = tid >> 4;
    const int lr = tid >> 2;          // tile row 0..63
    const int lk = (tid & 3) << 2;    // k offset 0..12

    long arow;
    {
        int m = m0 + lr;
        if (REMAP_A) arow = (long)((m % S_) * B_ + (m / S_)) * a_rs;
        else         arow = (long)m * a_rs;
    }
    const long brow = (long)(n0 + lr) * b_rs;

    float acc[4][4] = {};
    for (int k0 = 0; k0 < K; k0 += 16) {
        float4 av = *(const float4*)(Ab + arow + k0 + lk);
        float4 bv = *(const float4*)(Bb + brow + k0 + lk);
        As[lk + 0][lr] = av.x; As[lk + 1][lr] = av.y;
        As[lk + 2][lr] = av.z; As[lk + 3][lr] = av.w;
        Bs[lk + 0][lr] = bv.x; Bs[lk + 1][lr] = bv.y;
        Bs[lk + 2][lr] = bv.z; Bs[lk + 3][lr] = bv.w;
        __syncthreads();
#pragma unroll
        for (int kk = 0; kk < 16; ++kk) {
            float4 a = *(const float4*)&As[kk][ty << 2];
            float4 b = *(const float4*)&Bs[kk][tx << 2];
            acc[0][0] += a.x * b.x; acc[0][1] += a.x * b.y; acc[0][2] += a.x * b.z; acc[0][3] += a.x * b.w;
            acc[1][0] += a.y * b.x; acc[1][1] += a.y * b.y; acc[1][2] += a.y * b.z; acc[1][3] += a.y * b.w;
            acc[2][0] += a.z * b.x; acc[2][1] += a.z * b.y; acc[2][2] += a.z * b.z; acc[2][3] += a.z * b.w;
            acc[3][0] += a.w * b.x; acc[3][1] += a.w * b.y; acc[3][2] += a.w * b.z; acc[3][3] += a.w * b.w;
        }
        __syncthreads();
    }
#pragma unroll
    for (int i = 0; i < 4; ++i) {
        const int m = m0 + (ty << 2) + i;
#pragma unroll
        for (int j = 0; j < 4; ++j) {
            const int n = n0 + (tx << 2) + j;
            float v = acc[i][j];
            if (EPI == 1) v = tanhf(v + bias[n]);
            Cb[(long)m * c_rs + n] = v;
        }
    }
}

// ---------------------------------------------------------------------------
// bf16 helpers
// ---------------------------------------------------------------------------
__device__ inline unsigned short bf16_rtn(float x)
{
    unsigned u = __float_as_uint(x);
    u += 0x7FFFu + ((u >> 16) & 1);
    return (unsigned short)(u >> 16);
}

__device__ inline unsigned pk_bf16(float lo, float hi)
{
    return (unsigned)bf16_rtn(lo) | ((unsigned)bf16_rtn(hi) << 16);
}

// generic fp32 -> bf16 pack, 4 elems/thread
__global__ __launch_bounds__(256) void pack_bf16(const float* __restrict__ src,
                                                 unsigned short* __restrict__ dst,
                                                 long n4)
{
    const long i = (long)blockIdx.x * 256 + threadIdx.x;
    if (i >= n4) return;
    const float4 v = *((const float4*)src + i);
    uint2 u;
    u.x = pk_bf16(v.x, v.y);
    u.y = pk_bf16(v.z, v.w);
    *((uint2*)dst + i) = u;
}

// ---------------------------------------------------------------------------
// Softmax over r (last axis, contiguous, 512): one wave per row, in-place
// ---------------------------------------------------------------------------
__global__ __launch_bounds__(256) void softmax_rows(float* __restrict__ l)
{
    const int lane = threadIdx.x & 63;
    const int wv = threadIdx.x >> 6;
    const long row = (long)blockIdx.x * 4 + wv;
    float* p = l + row * R_;
    float4 v0 = ((const float4*)p)[lane * 2];
    float4 v1 = ((const float4*)p)[lane * 2 + 1];
    float m = fmaxf(fmaxf(fmaxf(v0.x, v0.y), fmaxf(v0.z, v0.w)),
                    fmaxf(fmaxf(v1.x, v1.y), fmaxf(v1.z, v1.w)));
#pragma unroll
    for (int o = 32; o; o >>= 1) m = fmaxf(m, __shfl_xor(m, o));
    v0.x = __expf(v0.x - m); v0.y = __expf(v0.y - m);
    v0.z = __expf(v0.z - m); v0.w = __expf(v0.w - m);
    v1.x = __expf(v1.x - m); v1.y = __expf(v1.y - m);
    v1.z = __expf(v1.z - m); v1.w = __expf(v1.w - m);
    float s = v0.x + v0.y + v0.z + v0.w + v1.x + v1.y + v1.z + v1.w;
#pragma unroll
    for (int o = 32; o; o >>= 1) s += __shfl_xor(s, o);
    const float inv = 1.f / s;
    v0.x *= inv; v0.y *= inv; v0.z *= inv; v0.w *= inv;
    v1.x *= inv; v1.y *= inv; v1.z *= inv; v1.w *= inv;
    ((float4*)p)[lane * 2] = v0;
    ((float4*)p)[lane * 2 + 1] = v1;
}

// ---------------------------------------------------------------------------
// Softmax over s (axis 1, stride R) -> bf16 output
// ---------------------------------------------------------------------------
__global__ __launch_bounds__(512) void softmax_cols(const float* __restrict__ l,
                                                    unsigned short* __restrict__ asb)
{
    const int b = blockIdx.y;
    const int rl = threadIdx.x & 127;
    const int r = blockIdx.x * 128 + rl;
    const int sg = threadIdx.x >> 7;           // 0..3
    const int s0 = sg * (S_ / 4), s1 = s0 + S_ / 4;
    const float* base = l + (long)b * S_ * R_ + r;
    __shared__ float red[4][128];

    float pm = -1e30f;
    for (int s = s0; s < s1; ++s) pm = fmaxf(pm, base[(long)s * R_]);
    red[sg][rl] = pm;
    __syncthreads();
    const float m = fmaxf(fmaxf(red[0][rl], red[1][rl]), fmaxf(red[2][rl], red[3][rl]));
    __syncthreads();

    float ps = 0.f;
    for (int s = s0; s < s1; ++s) ps += __expf(base[(long)s * R_] - m);
    red[sg][rl] = ps;
    __syncthreads();
    const float inv = 1.f / (red[0][rl] + red[1][rl] + red[2][rl] + red[3][rl]);

    unsigned short* ob = asb + (long)b * S_ * R_ + r;
    for (int s = s0; s < s1; ++s)
        ob[(long)s * R_] = bf16_rtn(__expf(base[(long)s * R_] - m) * inv);
}

// ---------------------------------------------------------------------------
// cat_bf rows 0..511: cat_bf[b][h][s] = bf16(h_s[b][s][h])
// ---------------------------------------------------------------------------
__global__ __launch_bounds__(256) void transpose_hs(const float* __restrict__ hs,
                                                    unsigned short* __restrict__ catb)
{
    __shared__ float tile[32][33];
    const int b = blockIdx.z;
    const int s0 = blockIdx.x * 32, h0 = blockIdx.y * 32;
    const int tx = threadIdx.x, ty = threadIdx.y;
#pragma unroll
    for (int i = 0; i < 32; i += 8)
        tile[ty + i][tx] = hs[((long)b * S_ + s0 + ty + i) * H_ + h0 + tx];
    __syncthreads();
#pragma unroll
    for (int i = 0; i < 32; i += 8)
        catb[((long)b * 2 * H_ + h0 + ty + i) * S_ + s0 + tx] = bf16_rtn(tile[tx][ty + i]);
}

// ---------------------------------------------------------------------------
// refT_bf[b][h][r] = bf16(ref[r][b][h])
// ---------------------------------------------------------------------------
__global__ __launch_bounds__(256) void transpose_ref(const float* __restrict__ ref,
                                                     unsigned short* __restrict__ refT)
{
    __shared__ float tile[32][33];
    const int b = blockIdx.z;
    const int r0 = blockIdx.x * 32, h0 = blockIdx.y * 32;
    const int tx = threadIdx.x, ty = threadIdx.y;
#pragma unroll
    for (int i = 0; i < 32; i += 8)
        tile[ty + i][tx] = ref[((long)(r0 + ty + i) * B_ + b) * H_ + h0 + tx];
    __syncthreads();
#pragma unroll
    for (int i = 0; i < 32; i += 8)
        refT[((long)b * H_ + h0 + ty + i) * R_ + r0 + tx] = bf16_rtn(tile[tx][ty + i]);
}

// ---------------------------------------------------------------------------
// a_rT_bf[b][r][s] = bf16(l[b][s][r])   (l holds a_r after softmax_rows)
// ---------------------------------------------------------------------------
__global__ __launch_bounds__(256) void transpose_arT(const float* __restrict__ l,
                                                     unsigned short* __restrict__ arT)
{
    __shared__ float tile[32][33];
    const int b = blockIdx.z;
    const int s0 = blockIdx.x * 32, r0 = blockIdx.y * 32;
    const int tx = threadIdx.x, ty = threadIdx.y;
#pragma unroll
    for (int i = 0; i < 32; i += 8)
        tile[ty + i][tx] = l[((long)b * S_ + s0 + ty + i) * R_ + r0 + tx];
    __syncthreads();
#pragma unroll
    for (int i = 0; i < 32; i += 8)
        arT[((long)b * R_ + r0 + ty + i) * S_ + s0 + tx] = bf16_rtn(tile[tx][ty + i]);
}

// ---------------------------------------------------------------------------
// bin_bf16[t*B+b][0:1024] = bf16(c_r[b][t][:]); [1024:1536] = bf16(ref[t][b][:])
// ---------------------------------------------------------------------------
__global__ __launch_bounds__(256) void build_bin(const float* __restrict__ cr,
                                                 const float* __restrict__ ref,
                                                 unsigned short* __restrict__ binb)
{
    const long idx4 = (long)blockIdx.x * blockDim.x + threadIdx.x;
    if (idx4 >= (long)R_ * B_ * DIN_ / 4) return;
    const long f = idx4 * 4;
    const int d = (int)(f % DIN_);
    const long tb = f / DIN_;
    const int b = (int)(tb % B_);
    const int t = (int)(tb / B_);
    float4 v;
    if (d < 2 * H_) v = *(const float4*)(cr + ((long)b * R_ + t) * (2 * H_) + d);
    else            v = *(const float4*)(ref + ((long)t * B_ + b) * H_ + (d - 2 * H_));
    uint2 u;
    u.x = pk_bf16(v.x, v.y);
    u.y = pk_bf16(v.z, v.w);
    *((uint2*)binb + idx4) = u;
}

// ---------------------------------------------------------------------------
// One-time W_hh transpose + bf16 pack: WB[dir][q2][g] (q2 = 4*kk + kgroup)
// ---------------------------------------------------------------------------
__global__ __launch_bounds__(256) void transpose_w_bf16(
    const float* __restrict__ Whh_f, const float* __restrict__ Whh_b,
    unsigned* __restrict__ WB)
{
    const int g = blockIdx.x * 256 + threadIdx.x;   // 0..1023
    const int q2 = blockIdx.y;                      // 0..31
    const int dir = blockIdx.z;
    const float* W = dir ? Whh_b : Whh_f;
    const float4 a = *(const float4*)(W + (long)g * HD_ + q2 * 8);
    const float4 b = *(const float4*)(W + (long)g * HD_ + q2 * 8 + 4);
    uint4 u;
    u.x = pk_bf16(a.x, a.y);
    u.y = pk_bf16(a.z, a.w);
    u.z = pk_bf16(b.x, b.y);
    u.w = pk_bf16(b.z, b.w);
    *((uint4*)WB + ((long)dir * 32 + q2) * 1024 + g) = u;
}

typedef __attribute__((ext_vector_type(4))) float f32x4;
typedef __attribute__((ext_vector_type(8))) short bf16x8;

__device__ inline bf16x8 u4_to_b8(uint4 u)
{
    bf16x8 r;
    __builtin_memcpy(&r, &u, 16);
    return r;
}

// ---------------------------------------------------------------------------
// Generic bf16 MFMA GEMM, 64x64 tile, batched, both operands k-contiguous.
// CT=0: bf16 row-major C[m][n]. CT=1: fp32 TRANSPOSED write C[n][m] (float4).
// ---------------------------------------------------------------------------
template<int CT>
__global__ __launch_bounds__(256) void gemm56(
    const unsigned short* __restrict__ A, long a_bs, int lda,
    const unsigned short* __restrict__ Bm, long b_bs, int ldb,
    void* __restrict__ Cv, long c_bs, int ldc, int K)
{
    const int bb = blockIdx.z;
    const int n0 = blockIdx.x * 64, m0 = blockIdx.y * 64;
    const int lane = threadIdx.x & 63, w = threadIdx.x >> 6;
    const int lr = lane & 15, lk = lane >> 4;
    const unsigned short* ap = A + bb * a_bs + (long)(m0 + lr) * lda + lk * 8;
    const unsigned short* bp = Bm + bb * b_bs + (long)(n0 + 16 * w + lr) * ldb + lk * 8;

    f32x4 acc[4];
#pragma unroll
    for (int mi = 0; mi < 4; ++mi) acc[mi] = (f32x4){0.f, 0.f, 0.f, 0.f};

    for (int k0 = 0; k0 < K; k0 += 32) {
        const bf16x8 bfr = *(const bf16x8*)(bp + k0);
#pragma unroll
        for (int mi = 0; mi < 4; ++mi) {
            const bf16x8 afr = *(const bf16x8*)(ap + (long)mi * 16 * lda + k0);
            acc[mi] = __builtin_amdgcn_mfma_f32_16x16x32_bf16(afr, bfr, acc[mi], 0, 0, 0);
        }
    }
    const int n = n0 + 16 * w + lr;
    if (CT == 0) {
        unsigned short* C = (unsigned short*)Cv + bb * c_bs;
#pragma unroll
        for (int mi = 0; mi < 4; ++mi)
#pragma unroll
            for (int r = 0; r < 4; ++r)
                C[(long)(m0 + 16 * mi + lk * 4 + r) * ldc + n] = bf16_rtn(acc[mi][r]);
    } else {
        float* C = (float*)Cv + bb * c_bs;
#pragma unroll
        for (int mi = 0; mi < 4; ++mi) {
            float4 v = make_float4(acc[mi][0], acc[mi][1], acc[mi][2], acc[mi][3]);
            *(float4*)&C[(long)n * ldc + m0 + 16 * mi + lk * 4] = v;
        }
    }
}

// ---------------------------------------------------------------------------
// Step-8 GEMM via MFMA: xg[m][n] = sum_k bin_bf[m][k]*Wih_bf[n][k] + bias(n)
// ---------------------------------------------------------------------------
__global__ __launch_bounds__(256) void gemm_xg_mfma(
    const unsigned short* __restrict__ binb, const unsigned short* __restrict__ Wb,
    const float* __restrict__ bihf, const float* __restrict__ bhhf,
    const float* __restrict__ bihb, const float* __restrict__ bhhb,
    float* __restrict__ xgf2, float* __restrict__ xgb2)
{
    const int dir = blockIdx.z;
    const int n0 = blockIdx.x * 64;
    const int m0 = blockIdx.y * 64;
    const int lane = threadIdx.x & 63, w = threadIdx.x >> 6;
    const int lr = lane & 15, lk = lane >> 4;
    const unsigned short* Wd = Wb + (long)dir * G_ * DIN_;
    const float* bi = dir ? bihb : bihf;
    const float* bh = dir ? bhhb : bhhf;
    float* xg = dir ? xgb2 : xgf2;

    const int n = n0 + 16 * w + lr;
    const unsigned short* bp = Wd + (long)n * DIN_ + lk * 8;
    const unsigned short* ap = binb + (long)(m0 + lr) * DIN_ + lk * 8;

    f32x4 acc[4];
#pragma unroll
    for (int mi = 0; mi < 4; ++mi) acc[mi] = (f32x4){0.f, 0.f, 0.f, 0.f};

    for (int k0 = 0; k0 < DIN_; k0 += 32) {
        const bf16x8 bfr = *(const bf16x8*)(bp + k0);
#pragma unroll
        for (int mi = 0; mi < 4; ++mi) {
            const bf16x8 afr = *(const bf16x8*)(ap + (long)mi * 16 * DIN_ + k0);
            acc[mi] = __builtin_amdgcn_mfma_f32_16x16x32_bf16(afr, bfr, acc[mi], 0, 0, 0);
        }
    }
    const float bias = bi[n] + bh[n];
#pragma unroll
    for (int mi = 0; mi < 4; ++mi)
#pragma unroll
        for (int r = 0; r < 4; ++r) {
            const int m = m0 + 16 * mi + lk * 4 + r;
            xg[(long)m * G_ + n] = acc[mi][r] + bias;
        }
}

// ---------------------------------------------------------------------------
// Bi-LSTM scan v12 — W fully LDS-resident (R18-proven structure) with the h
// exchange moved to AGENT-SCOPE RELAXED ATOMICS (LLC-direct, bypassing the
// per-XCD L2 in both directions) -> the per-step __threadfence (buffer_wbl2)
// and acquire-fence (L2 invalidate) are ELIMINATED. Correctness: writer's
// atomic u32 stores are drained (vmcnt(0)) by __syncthreads before tid0's
// flag store; reader polls the flag, __syncthreads (compiler memory barrier,
// no hoisting), then atomic u32 loads hit LLC where the data lives - no
// stale-cache path exists. Flag protocol otherwise identical to R7/R18.
// Own 64-col slice is written straight to the double-buffered h_lds during
// the cell phase; the stage phase fetches only the other 3 blocks' slices.
// ---------------------------------------------------------------------------
#define NBD 4

__device__ inline float sig_(float x) { return 1.f / (1.f + __expf(-x)); }

__global__ __launch_bounds__(256) void lstm_scan_s(
    const float* __restrict__ xg_f, const float* __restrict__ xg_b,
    const uint4* __restrict__ WBu, unsigned* __restrict__ hbu32,
    unsigned* __restrict__ flags, float* __restrict__ out)
{
    const int blk = blockIdx.x;
    const int dir = blk >> 2;
    const int j = blk & 3;
    const float* xg = dir ? xg_b : xg_f;
    const uint4* Wg = WBu + (long)dir * 32768;        // [q2 0..31][g 0..1023]
    unsigned* hbu = hbu32 + dir * 4096;               // [2 parity][16][128] u32
    unsigned* fl = flags + dir * 64;

    __shared__ uint4 WL[32 * 256];                    // 128 KB (full W slice)
    __shared__ unsigned short h_lds[2][16 * 264];     // 16.5 KB dbuf staged h

    const int tid = threadIdx.x;
    const int lane = tid & 63, w = tid >> 6;          // 4 waves
    const int lcol = lane & 15, lkg = lane >> 4;

    // fill WL once: local row = g*64 + c  <-  global gate row g*256 + 64j + c
    for (int idx = tid; idx < 32 * 256; idx += 256) {
        const int q2 = idx >> 8, loc = idx & 255;
        const int g = loc >> 6, c = loc & 63;
        WL[idx] = Wg[q2 * 1024 + g * 256 + 64 * j + c];
    }
    for (int i = tid; i < 16 * 264; i += 256) h_lds[0][i] = 0;
    float c_reg[4] = {};
    const int col = 64 * j + 16 * w + lcol;           // owned h-column
    __syncthreads();

    for (int t = 0; t < R_; ++t) {
        const int tt = dir ? (R_ - 1 - t) : t;
        const int p = t & 1;

        // prefetch xg (immutable; latency hides under the flag poll)
        float xgv[4][4];
#pragma unroll
        for (int g = 0; g < 4; ++g)
#pragma unroll
            for (int r = 0; r < 4; ++r)
                xgv[g][r] = xg[((long)tt * B_ + lkg * 4 + r) * G_ + g * 256 + col];

        if (t > 0) {
            if (tid < 64) {
                while (true) {
                    unsigned v = (lane < NBD)
                        ? __hip_atomic_load(&fl[lane * 16], __ATOMIC_RELAXED,
                                            __HIP_MEMORY_SCOPE_AGENT)
                        : 0xFFFFFFFFu;
                    if (__all(v >= (unsigned)t)) break;
                    __builtin_amdgcn_s_sleep(1);
                }
            }
            __syncthreads();   // barrier orders stage loads after the poll

            // stage the OTHER 3 blocks' slices: 1536 u32 LLC-direct loads
            for (int i = tid; i < 1536; i += 256) {
                const int b = i / 96, k = i - (i / 96) * 96;
                const int sl = k >> 5;
                const int jo = sl + (sl >= j);
                const int ku = 32 * jo + (k & 31);
                const unsigned v = __hip_atomic_load(
                    &hbu[p * 2048 + b * 128 + ku],
                    __ATOMIC_RELAXED, __HIP_MEMORY_SCOPE_AGENT);
                *(unsigned*)&h_lds[p][b * 264 + 2 * ku] = v;
            }
            __syncthreads();
        }

        // dot: wave w's 4 gate tiles, all LDS-fed
        f32x4 acc[4];
#pragma unroll
        for (int g = 0; g < 4; ++g) acc[g] = (f32x4){0.f, 0.f, 0.f, 0.f};
        const unsigned short* hrow = &h_lds[p][lcol * 264 + lkg * 8];
#pragma unroll
        for (int kk = 0; kk < 8; ++kk) {
            const bf16x8 a_ = *(const bf16x8*)(hrow + 32 * kk);
#pragma unroll
            for (int g = 0; g < 4; ++g) {
                const uint4 wv = WL[(4 * kk + lkg) * 256 + g * 64 + 16 * w + lcol];
                acc[g] = __builtin_amdgcn_mfma_f32_16x16x32_bf16(
                    a_, u4_to_b8(wv), acc[g], 0, 0, 0);
            }
        }

        // cell: lane owns (batch = lkg*4+r, col); own slice -> LDS dbuf;
        // paired-lane u32 atomic stores -> LLC (no fence needed)
        float hsv[4];
#pragma unroll
        for (int r = 0; r < 4; ++r) {
            const int batch = lkg * 4 + r;
            const float iv = acc[0][r] + xgv[0][r];
            const float fv = acc[1][r] + xgv[1][r];
            const float gv = acc[2][r] + xgv[2][r];
            const float ov = acc[3][r] + xgv[3][r];
            float ax = fabsf(gv);
            float tg = copysignf(1.f - 2.f / (1.f + __expf(2.f * ax)), gv);
            float c = sig_(fv) * c_reg[r] + sig_(iv) * tg;
            c_reg[r] = c;
            float ac = fabsf(c);
            float tc = copysignf(1.f - 2.f / (1.f + __expf(2.f * ac)), c);
            const float h = sig_(ov) * tc;
            hsv[r] = h;
            const unsigned short hb16 = bf16_rtn(h);
            h_lds[p ^ 1][batch * 264 + col] = hb16;
            const unsigned nb = (unsigned)__shfl_xor((int)(unsigned)hb16, 1);
            if ((lcol & 1) == 0) {
                const unsigned pkd = (unsigned)hb16 | (nb << 16);
                __hip_atomic_store(&hbu[(p ^ 1) * 2048 + batch * 128 + (col >> 1)],
                                   pkd, __ATOMIC_RELAXED, __HIP_MEMORY_SCOPE_AGENT);
            }
        }
        __syncthreads();   // vmcnt(0) drain: all atomic h stores at LLC
        if (tid == 0)
            __hip_atomic_store(&fl[j * 16], (unsigned)(t + 1), __ATOMIC_RELAXED,
                               __HIP_MEMORY_SCOPE_AGENT);
        // deferred out writes: off the flag critical path
#pragma unroll
        for (int r = 0; r < 4; ++r)
            out[((long)tt * B_ + lkg * 4 + r) * (2 * HD_) + dir * HD_ + col] = hsv[r];
    }
}

// ---------------------------------------------------------------------------
extern "C" void kernel_launch(void* const* d_in, const int* in_sizes, int n_in,
                              void* d_out, int out_size, void* d_ws, size_t ws_size,
                              hipStream_t stream)
{
    const float* src  = (const float*)d_in[1];   // [S][B][H]
    const float* ref  = (const float*)d_in[2];   // [R][B][H]
    const float* Wref = (const float*)d_in[3];   // [H][H]
    const float* bref = (const float*)d_in[4];   // [H]
    const float* Wihf = (const float*)d_in[5];   // [G][DIN]
    const float* Whhf = (const float*)d_in[6];   // [G][HD]
    const float* bihf = (const float*)d_in[7];
    const float* bhhf = (const float*)d_in[8];
    const float* Wihb = (const float*)d_in[9];
    const float* Whhb = (const float*)d_in[10];
    const float* bihb = (const float*)d_in[11];
    const float* bhhb = (const float*)d_in[12];
    float* out = (float*)d_out;                  // [R][B][2*HD]

    float* ws = (float*)d_ws;
    // workspace layout (float offsets):
    float* hs   = ws + 0L;                              // 8388608  [B][S][H]
    float* l    = ws + 8388608L;                        // 8388608  [B][S][R]
    unsigned short* as_bf = (unsigned short*)(ws + 16777216L);  // bf16 [B][S][R]
    unsigned short* refT  = (unsigned short*)(ws + 20971520L);  // bf16 [B][H][R]
    unsigned short* a_rT  = (unsigned short*)(ws + 23068672L);  // bf16 [B][R][S]
    unsigned short* catb  = (unsigned short*)(ws + 27262976L);  // bf16 [B][2H][S]
    unsigned short* binb  = (unsigned short*)(ws + 35651584L);  // bf16 [T*B][DIN]
    unsigned* WB = (unsigned*)(ws + 41943040L);         // 1 MB scan W bf16
    unsigned short* Wib = (unsigned short*)(ws + 42205184L);    // 6 MB W_ih bf16
    unsigned* hbu32 = (unsigned*)(ws + 43778048L);      // 32 KB h dbuf (u32 view)
    unsigned* flags = (unsigned*)(ws + 43786240L);      // 512 B
    float* cr  = hs;                                    // alias (hs dead after step 4)
    float* xgf = l;                                     // alias (l dead after a_rT)
    float* xgb = ws + 16777216L;                        // alias (dead after step 6)

    // zero h_0 + flags
    hipMemsetAsync(hbu32, 0, 2 * 2 * B_ * HD_ * 2 + 512, stream);

    // 0) one-time weight packs
    transpose_w_bf16<<<dim3(4, 32, 2), 256, 0, stream>>>(Whhf, Whhb, WB);
    pack_bf16<<<dim3((G_ * DIN_ / 4 + 255) / 256), 256, 0, stream>>>(
        Wihf, Wib, (long)G_ * DIN_ / 4);
    pack_bf16<<<dim3((G_ * DIN_ / 4 + 255) / 256), 256, 0, stream>>>(
        Wihb, Wib + (long)G_ * DIN_, (long)G_ * DIN_ / 4);

    // 1) h_s = tanh(src . Wref^T + bref)
    gemm_mk_nk<1, 1><<<dim3(8, 256, 1), 256, 0, stream>>>(
        src, H_, 0, Wref, H_, 0, hs, H_, 0, bref, B_ * S_, H_, H_);

    // 2) l[b] = h_s[b] . h_r[b]^T
    gemm_mk_nk<0, 0><<<dim3(8, 16, B_), 256, 0, stream>>>(
        hs, H_, (long)S_ * H_, ref, (long)B_ * H_, H_, l, R_, (long)S_ * R_,
        nullptr, S_, R_, H_);

    // 3) softmaxes: a_s -> bf16; a_r in place (fp32)
    softmax_cols<<<dim3(R_ / 128, B_), 512, 0, stream>>>(l, as_bf);
    softmax_rows<<<(B_ * S_) / 4, 256, 0, stream>>>(l);

    // 3b) bf16 transposes for the MFMA attention GEMMs
    transpose_ref<<<dim3(R_ / 32, H_ / 32, B_), dim3(32, 8), 0, stream>>>(ref, refT);
    transpose_arT<<<dim3(S_ / 32, R_ / 32, B_), dim3(32, 8), 0, stream>>>(l, a_rT);

    // 4) cat_bf rows 0..511 = h_s^T (bf16)
    transpose_hs<<<dim3(S_ / 32, H_ / 32, B_), dim3(32, 8), 0, stream>>>(hs, catb);

    // 5) cat_bf rows 512..1023: c_s[b,h,s] = sum_r refT[b,h,r]*a_s[b,s,r]  (MFMA)
    gemm56<0><<<dim3(S_ / 64, H_ / 64, B_), 256, 0, stream>>>(
        refT, (long)H_ * R_, R_, as_bf, (long)S_ * R_, R_,
        (void*)(catb + (long)H_ * S_), (long)2 * H_ * S_, S_, R_);

    // 6) c_r[b,r,m] = sum_s cat_bf[b,m,s]*a_rT[b,r,s]  (MFMA, transposed C)
    gemm56<1><<<dim3(R_ / 64, 2 * H_ / 64, B_), 256, 0, stream>>>(
        catb, (long)2 * H_ * S_, S_, a_rT, (long)R_ * S_, S_,
        (void*)cr, (long)R_ * 2 * H_, 2 * H_, S_);

    // 7) bilstm_in -> bf16
    build_bin<<<(R_ * B_ * DIN_ / 4 + 255) / 256, 256, 0, stream>>>(cr, ref, binb);

    // 8) xg = bin . W_ih^T + b_ih + b_hh  via MFMA
    gemm_xg_mfma<<<dim3(G_ / 64, R_ * B_ / 64, 2), 256, 0, stream>>>(
        binb, Wib, bihf, bhhf, bihb, bhhb, xgf, xgb);

    // 9) bi-LSTM scan: 4 blocks/dir, W LDS-resident, fence-free atomic h sync
    lstm_scan_s<<<dim3(2 * NBD), dim3(256), 0, stream>>>(
        xgf, xgb, (const uint4*)WB, hbu32, flags, out);
}

// Round 21
// 2842.651 us; speedup vs baseline: 1.1443x; 1.1443x over previous
//
#include <hip/hip_runtime.h>
#include <hip/hip_bf16.h>
#include <math.h>

#define B_   16
#define S_   1024
#define R_   512
#define H_   512
#define HD_  256
#define G_   1024
#define DIN_ 1536

// ---------------------------------------------------------------------------
// Tiled fp32 GEMM:  C[m][n] = sum_k A(m,k) * B(n,k)   (steps 1 and 2 only)
// ---------------------------------------------------------------------------
template<int EPI, int REMAP_A>
__global__ __launch_bounds__(256) void gemm_mk_nk(
    const float* __restrict__ A, long a_rs, long a_bs,
    const float* __restrict__ Bm, long b_rs, long b_bs,
    float* __restrict__ C, long c_rs, long c_bs,
    const float* __restrict__ bias,
    int M, int N, int K)
{
    __shared__ float As[16][68];
    __shared__ float Bs[16][68];
    const int bb = blockIdx.z;
    const float* Ab = A + (long)bb * a_bs;
    const float* Bb = Bm + (long)bb * b_bs;
    float* Cb = C + (long)bb * c_bs;
    const int m0 = blockIdx.y * 64, n0 = blockIdx.x * 64;
    const int tid = threadIdx.x;
    const int tx = tid & 15, ty = tid >> 4;
    const int lr = tid >> 2;          // tile row 0..63
    const int lk = (tid & 3) << 2;    // k offset 0..12

    long arow;
    {
        int m = m0 + lr;
        if (REMAP_A) arow = (long)((m % S_) * B_ + (m / S_)) * a_rs;
        else         arow = (long)m * a_rs;
    }
    const long brow = (long)(n0 + lr) * b_rs;

    float acc[4][4] = {};
    for (int k0 = 0; k0 < K; k0 += 16) {
        float4 av = *(const float4*)(Ab + arow + k0 + lk);
        float4 bv = *(const float4*)(Bb + brow + k0 + lk);
        As[lk + 0][lr] = av.x; As[lk + 1][lr] = av.y;
        As[lk + 2][lr] = av.z; As[lk + 3][lr] = av.w;
        Bs[lk + 0][lr] = bv.x; Bs[lk + 1][lr] = bv.y;
        Bs[lk + 2][lr] = bv.z; Bs[lk + 3][lr] = bv.w;
        __syncthreads();
#pragma unroll
        for (int kk = 0; kk < 16; ++kk) {
            float4 a = *(const float4*)&As[kk][ty << 2];
            float4 b = *(const float4*)&Bs[kk][tx << 2];
            acc[0][0] += a.x * b.x; acc[0][1] += a.x * b.y; acc[0][2] += a.x * b.z; acc[0][3] += a.x * b.w;
            acc[1][0] += a.y * b.x; acc[1][1] += a.y * b.y; acc[1][2] += a.y * b.z; acc[1][3] += a.y * b.w;
            acc[2][0] += a.z * b.x; acc[2][1] += a.z * b.y; acc[2][2] += a.z * b.z; acc[2][3] += a.z * b.w;
            acc[3][0] += a.w * b.x; acc[3][1] += a.w * b.y; acc[3][2] += a.w * b.z; acc[3][3] += a.w * b.w;
        }
        __syncthreads();
    }
#pragma unroll
    for (int i = 0; i < 4; ++i) {
        const int m = m0 + (ty << 2) + i;
#pragma unroll
        for (int j = 0; j < 4; ++j) {
            const int n = n0 + (tx << 2) + j;
            float v = acc[i][j];
            if (EPI == 1) v = tanhf(v + bias[n]);
            Cb[(long)m * c_rs + n] = v;
        }
    }
}

// ---------------------------------------------------------------------------
// bf16 helpers
// ---------------------------------------------------------------------------
__device__ inline unsigned short bf16_rtn(float x)
{
    unsigned u = __float_as_uint(x);
    u += 0x7FFFu + ((u >> 16) & 1);
    return (unsigned short)(u >> 16);
}

__device__ inline unsigned pk_bf16(float lo, float hi)
{
    return (unsigned)bf16_rtn(lo) | ((unsigned)bf16_rtn(hi) << 16);
}

// generic fp32 -> bf16 pack, 4 elems/thread
__global__ __launch_bounds__(256) void pack_bf16(const float* __restrict__ src,
                                                 unsigned short* __restrict__ dst,
                                                 long n4)
{
    const long i = (long)blockIdx.x * 256 + threadIdx.x;
    if (i >= n4) return;
    const float4 v = *((const float4*)src + i);
    uint2 u;
    u.x = pk_bf16(v.x, v.y);
    u.y = pk_bf16(v.z, v.w);
    *((uint2*)dst + i) = u;
}

// ---------------------------------------------------------------------------
// Fill the STATIC half of bin: binb[row][1024+d] = bf16(ref[row*H+d]),
// row = t*B+b (ref rows map 1:1 to bin rows). Runs once per launch.
// ---------------------------------------------------------------------------
__global__ __launch_bounds__(256) void pack_ref_bin(const float* __restrict__ ref,
                                                    unsigned short* __restrict__ binb)
{
    const long idx4 = (long)blockIdx.x * 256 + threadIdx.x;
    if (idx4 >= (long)R_ * B_ * H_ / 4) return;
    const long f = idx4 * 4;
    const long row = f / H_;
    const int d = (int)(f % H_);
    const float4 v = *(const float4*)(ref + f);
    uint2 u;
    u.x = pk_bf16(v.x, v.y);
    u.y = pk_bf16(v.z, v.w);
    *(uint2*)&binb[row * DIN_ + 2 * H_ + d] = u;
}

// ---------------------------------------------------------------------------
// Softmax over r (last axis, contiguous, 512): one wave per row, in-place
// ---------------------------------------------------------------------------
__global__ __launch_bounds__(256) void softmax_rows(float* __restrict__ l)
{
    const int lane = threadIdx.x & 63;
    const int wv = threadIdx.x >> 6;
    const long row = (long)blockIdx.x * 4 + wv;
    float* p = l + row * R_;
    float4 v0 = ((const float4*)p)[lane * 2];
    float4 v1 = ((const float4*)p)[lane * 2 + 1];
    float m = fmaxf(fmaxf(fmaxf(v0.x, v0.y), fmaxf(v0.z, v0.w)),
                    fmaxf(fmaxf(v1.x, v1.y), fmaxf(v1.z, v1.w)));
#pragma unroll
    for (int o = 32; o; o >>= 1) m = fmaxf(m, __shfl_xor(m, o));
    v0.x = __expf(v0.x - m); v0.y = __expf(v0.y - m);
    v0.z = __expf(v0.z - m); v0.w = __expf(v0.w - m);
    v1.x = __expf(v1.x - m); v1.y = __expf(v1.y - m);
    v1.z = __expf(v1.z - m); v1.w = __expf(v1.w - m);
    float s = v0.x + v0.y + v0.z + v0.w + v1.x + v1.y + v1.z + v1.w;
#pragma unroll
    for (int o = 32; o; o >>= 1) s += __shfl_xor(s, o);
    const float inv = 1.f / s;
    v0.x *= inv; v0.y *= inv; v0.z *= inv; v0.w *= inv;
    v1.x *= inv; v1.y *= inv; v1.z *= inv; v1.w *= inv;
    ((float4*)p)[lane * 2] = v0;
    ((float4*)p)[lane * 2 + 1] = v1;
}

// ---------------------------------------------------------------------------
// Softmax over s (axis 1, stride R) -> bf16 output
// ---------------------------------------------------------------------------
__global__ __launch_bounds__(512) void softmax_cols(const float* __restrict__ l,
                                                    unsigned short* __restrict__ asb)
{
    const int b = blockIdx.y;
    const int rl = threadIdx.x & 127;
    const int r = blockIdx.x * 128 + rl;
    const int sg = threadIdx.x >> 7;           // 0..3
    const int s0 = sg * (S_ / 4), s1 = s0 + S_ / 4;
    const float* base = l + (long)b * S_ * R_ + r;
    __shared__ float red[4][128];

    float pm = -1e30f;
    for (int s = s0; s < s1; ++s) pm = fmaxf(pm, base[(long)s * R_]);
    red[sg][rl] = pm;
    __syncthreads();
    const float m = fmaxf(fmaxf(red[0][rl], red[1][rl]), fmaxf(red[2][rl], red[3][rl]));
    __syncthreads();

    float ps = 0.f;
    for (int s = s0; s < s1; ++s) ps += __expf(base[(long)s * R_] - m);
    red[sg][rl] = ps;
    __syncthreads();
    const float inv = 1.f / (red[0][rl] + red[1][rl] + red[2][rl] + red[3][rl]);

    unsigned short* ob = asb + (long)b * S_ * R_ + r;
    for (int s = s0; s < s1; ++s)
        ob[(long)s * R_] = bf16_rtn(__expf(base[(long)s * R_] - m) * inv);
}

// ---------------------------------------------------------------------------
// cat_bf rows 0..511: cat_bf[b][h][s] = bf16(h_s[b][s][h])
// ---------------------------------------------------------------------------
__global__ __launch_bounds__(256) void transpose_hs(const float* __restrict__ hs,
                                                    unsigned short* __restrict__ catb)
{
    __shared__ float tile[32][33];
    const int b = blockIdx.z;
    const int s0 = blockIdx.x * 32, h0 = blockIdx.y * 32;
    const int tx = threadIdx.x, ty = threadIdx.y;
#pragma unroll
    for (int i = 0; i < 32; i += 8)
        tile[ty + i][tx] = hs[((long)b * S_ + s0 + ty + i) * H_ + h0 + tx];
    __syncthreads();
#pragma unroll
    for (int i = 0; i < 32; i += 8)
        catb[((long)b * 2 * H_ + h0 + ty + i) * S_ + s0 + tx] = bf16_rtn(tile[tx][ty + i]);
}

// ---------------------------------------------------------------------------
// refT_bf[b][h][r] = bf16(ref[r][b][h])
// ---------------------------------------------------------------------------
__global__ __launch_bounds__(256) void transpose_ref(const float* __restrict__ ref,
                                                     unsigned short* __restrict__ refT)
{
    __shared__ float tile[32][33];
    const int b = blockIdx.z;
    const int r0 = blockIdx.x * 32, h0 = blockIdx.y * 32;
    const int tx = threadIdx.x, ty = threadIdx.y;
#pragma unroll
    for (int i = 0; i < 32; i += 8)
        tile[ty + i][tx] = ref[((long)(r0 + ty + i) * B_ + b) * H_ + h0 + tx];
    __syncthreads();
#pragma unroll
    for (int i = 0; i < 32; i += 8)
        refT[((long)b * H_ + h0 + ty + i) * R_ + r0 + tx] = bf16_rtn(tile[tx][ty + i]);
}

// ---------------------------------------------------------------------------
// a_rT_bf[b][r][s] = bf16(l[b][s][r])   (l holds a_r after softmax_rows)
// ---------------------------------------------------------------------------
__global__ __launch_bounds__(256) void transpose_arT(const float* __restrict__ l,
                                                     unsigned short* __restrict__ arT)
{
    __shared__ float tile[32][33];
    const int b = blockIdx.z;
    const int s0 = blockIdx.x * 32, r0 = blockIdx.y * 32;
    const int tx = threadIdx.x, ty = threadIdx.y;
#pragma unroll
    for (int i = 0; i < 32; i += 8)
        tile[ty + i][tx] = l[((long)b * S_ + s0 + ty + i) * R_ + r0 + tx];
    __syncthreads();
#pragma unroll
    for (int i = 0; i < 32; i += 8)
        arT[((long)b * R_ + r0 + ty + i) * S_ + s0 + tx] = bf16_rtn(tile[tx][ty + i]);
}

// ---------------------------------------------------------------------------
// One-time W_hh transpose + bf16 pack: WB[dir][q2][g] (q2 = 4*kk + kgroup)
// ---------------------------------------------------------------------------
__global__ __launch_bounds__(256) void transpose_w_bf16(
    const float* __restrict__ Whh_f, const float* __restrict__ Whh_b,
    unsigned* __restrict__ WB)
{
    const int g = blockIdx.x * 256 + threadIdx.x;   // 0..1023
    const int q2 = blockIdx.y;                      // 0..31
    const int dir = blockIdx.z;
    const float* W = dir ? Whh_b : Whh_f;
    const float4 a = *(const float4*)(W + (long)g * HD_ + q2 * 8);
    const float4 b = *(const float4*)(W + (long)g * HD_ + q2 * 8 + 4);
    uint4 u;
    u.x = pk_bf16(a.x, a.y);
    u.y = pk_bf16(a.z, a.w);
    u.z = pk_bf16(b.x, b.y);
    u.w = pk_bf16(b.z, b.w);
    *((uint4*)WB + ((long)dir * 32 + q2) * 1024 + g) = u;
}

typedef __attribute__((ext_vector_type(4))) float f32x4;
typedef __attribute__((ext_vector_type(8))) short bf16x8;

__device__ inline bf16x8 u4_to_b8(uint4 u)
{
    bf16x8 r;
    __builtin_memcpy(&r, &u, 16);
    return r;
}

// ---------------------------------------------------------------------------
// Generic bf16 MFMA GEMM, 64x64 tile, batched, both operands k-contiguous.
// CT=0: bf16 row-major C[m][n] (ldc = row stride).
// CT=1: bf16 TRANSPOSED write C[n][m] (uint2 of 4 bf16); ldc = per-n stride.
//       Used by step 6 to write c_r DIRECTLY into bin (row = r*B+b), which
//       eliminates the build_bin pass (~92 MB of traffic).
// ---------------------------------------------------------------------------
template<int CT>
__global__ __launch_bounds__(256) void gemm56(
    const unsigned short* __restrict__ A, long a_bs, int lda,
    const unsigned short* __restrict__ Bm, long b_bs, int ldb,
    unsigned short* __restrict__ Cv, long c_bs, long ldc, int K)
{
    const int bb = blockIdx.z;
    const int n0 = blockIdx.x * 64, m0 = blockIdx.y * 64;
    const int lane = threadIdx.x & 63, w = threadIdx.x >> 6;
    const int lr = lane & 15, lk = lane >> 4;
    const unsigned short* ap = A + bb * a_bs + (long)(m0 + lr) * lda + lk * 8;
    const unsigned short* bp = Bm + bb * b_bs + (long)(n0 + 16 * w + lr) * ldb + lk * 8;

    f32x4 acc[4];
#pragma unroll
    for (int mi = 0; mi < 4; ++mi) acc[mi] = (f32x4){0.f, 0.f, 0.f, 0.f};

    for (int k0 = 0; k0 < K; k0 += 32) {
        const bf16x8 bfr = *(const bf16x8*)(bp + k0);
#pragma unroll
        for (int mi = 0; mi < 4; ++mi) {
            const bf16x8 afr = *(const bf16x8*)(ap + (long)mi * 16 * lda + k0);
            acc[mi] = __builtin_amdgcn_mfma_f32_16x16x32_bf16(afr, bfr, acc[mi], 0, 0, 0);
        }
    }
    const int n = n0 + 16 * w + lr;
    unsigned short* C = Cv + bb * c_bs;
    if (CT == 0) {
#pragma unroll
        for (int mi = 0; mi < 4; ++mi)
#pragma unroll
            for (int r = 0; r < 4; ++r)
                C[(long)(m0 + 16 * mi + lk * 4 + r) * ldc + n] = bf16_rtn(acc[mi][r]);
    } else {
#pragma unroll
        for (int mi = 0; mi < 4; ++mi) {
            uint2 u;
            u.x = pk_bf16(acc[mi][0], acc[mi][1]);
            u.y = pk_bf16(acc[mi][2], acc[mi][3]);
            *(uint2*)&C[(long)n * ldc + m0 + 16 * mi + lk * 4] = u;
        }
    }
}

// ---------------------------------------------------------------------------
// Step-8 GEMM via MFMA: xg[m][n] = sum_k bin_bf[m][k]*Wih_bf[n][k] + bias(n)
// ---------------------------------------------------------------------------
__global__ __launch_bounds__(256) void gemm_xg_mfma(
    const unsigned short* __restrict__ binb, const unsigned short* __restrict__ Wb,
    const float* __restrict__ bihf, const float* __restrict__ bhhf,
    const float* __restrict__ bihb, const float* __restrict__ bhhb,
    float* __restrict__ xgf2, float* __restrict__ xgb2)
{
    const int dir = blockIdx.z;
    const int n0 = blockIdx.x * 64;
    const int m0 = blockIdx.y * 64;
    const int lane = threadIdx.x & 63, w = threadIdx.x >> 6;
    const int lr = lane & 15, lk = lane >> 4;
    const unsigned short* Wd = Wb + (long)dir * G_ * DIN_;
    const float* bi = dir ? bihb : bihf;
    const float* bh = dir ? bhhb : bhhf;
    float* xg = dir ? xgb2 : xgf2;

    const int n = n0 + 16 * w + lr;
    const unsigned short* bp = Wd + (long)n * DIN_ + lk * 8;
    const unsigned short* ap = binb + (long)(m0 + lr) * DIN_ + lk * 8;

    f32x4 acc[4];
#pragma unroll
    for (int mi = 0; mi < 4; ++mi) acc[mi] = (f32x4){0.f, 0.f, 0.f, 0.f};

    for (int k0 = 0; k0 < DIN_; k0 += 32) {
        const bf16x8 bfr = *(const bf16x8*)(bp + k0);
#pragma unroll
        for (int mi = 0; mi < 4; ++mi) {
            const bf16x8 afr = *(const bf16x8*)(ap + (long)mi * 16 * DIN_ + k0);
            acc[mi] = __builtin_amdgcn_mfma_f32_16x16x32_bf16(afr, bfr, acc[mi], 0, 0, 0);
        }
    }
    const float bias = bi[n] + bh[n];
#pragma unroll
    for (int mi = 0; mi < 4; ++mi)
#pragma unroll
        for (int r = 0; r < 4; ++r) {
            const int m = m0 + 16 * mi + lk * 4 + r;
            xg[(long)m * G_ + n] = acc[mi][r] + bias;
        }
}

// ---------------------------------------------------------------------------
// Bi-LSTM scan — R18's EXACT kernel (empirically fastest of 4 variants:
// R18 fence-protocol 1795us < R19 dbuf/deferred 1816us < R20 atomics 2185us).
// W fully LDS-resident: 4 blocks/direction x 256 thr; block (dir,j) owns
// h-cols [64j,64j+64) x ALL 4 gates; cell is lane-local; cross-block h via
// global hbuf (double-buffered) + R7-proven flag sync.
// ---------------------------------------------------------------------------
#define NBD 4

__device__ inline float sig_(float x) { return 1.f / (1.f + __expf(-x)); }
__device__ inline float tanh_(float x) {
    float ax = fabsf(x);
    float t = 1.f - 2.f / (1.f + __expf(2.f * ax));
    return copysignf(t, x);
}

__global__ __launch_bounds__(256) void lstm_scan_s(
    const float* __restrict__ xg_f, const float* __restrict__ xg_b,
    const uint4* __restrict__ WBu, unsigned short* __restrict__ hbuf,
    unsigned* __restrict__ flags, float* __restrict__ out)
{
    const int blk = blockIdx.x;
    const int dir = blk >> 2;
    const int j = blk & 3;
    const float* xg = dir ? xg_b : xg_f;
    const uint4* Wg = WBu + (long)dir * 32768;        // [q2 0..31][g 0..1023]
    unsigned short* hb = hbuf + dir * (2 * B_ * HD_); // 2 parity x [16][256]
    unsigned* fl = flags + dir * 64;

    __shared__ uint4 WL[32 * 256];                    // 128 KB (full W slice)
    __shared__ unsigned short h_lds[16 * 264];        // 8.25 KB staged h

    const int tid = threadIdx.x;
    const int lane = tid & 63, w = tid >> 6;          // 4 waves
    const int lcol = lane & 15, lkg = lane >> 4;

    // fill WL once: local row = g*64 + c  <-  global gate row g*256 + 64j + c
    for (int idx = tid; idx < 32 * 256; idx += 256) {
        const int q2 = idx >> 8, loc = idx & 255;
        const int g = loc >> 6, c = loc & 63;
        WL[idx] = Wg[q2 * 1024 + g * 256 + 64 * j + c];
    }
    float c_reg[4] = {};
    const int col = 64 * j + 16 * w + lcol;           // owned h-column
    __syncthreads();

    for (int t = 0; t < R_; ++t) {
        const int tt = dir ? (R_ - 1 - t) : t;
        const int p = t & 1;

        // prefetch xg (immutable data -> safe before the acquire fence;
        // HBM/LLC latency hides under the flag poll)
        float xgv[4][4];
#pragma unroll
        for (int g = 0; g < 4; ++g)
#pragma unroll
            for (int r = 0; r < 4; ++r)
                xgv[g][r] = xg[((long)tt * B_ + lkg * 4 + r) * G_ + g * 256 + col];

        if (t > 0) {
            if (tid < 64) {
                while (true) {
                    unsigned v = (lane < NBD)
                        ? __hip_atomic_load(&fl[lane * 16], __ATOMIC_RELAXED,
                                            __HIP_MEMORY_SCOPE_AGENT)
                        : 0xFFFFFFFFu;
                    if (__all(v >= (unsigned)t)) break;
                    __builtin_amdgcn_s_sleep(1);
                }
            }
            __syncthreads();
            __builtin_amdgcn_fence(__ATOMIC_ACQUIRE, "agent");
        }

        // stage h_t (parity p) -> LDS  (16 rows x 256 bf16; 512 uint4)
        for (int i = tid; i < 512; i += 256) {
            const int b = i >> 5, c8 = (i & 31) * 8;
            *(uint4*)&h_lds[b * 264 + c8] =
                *(const uint4*)&hb[p * (B_ * HD_) + b * HD_ + c8];
        }
        __syncthreads();

        // dot: wave w's 4 gate tiles (rows g*64+16w..+16 local), all LDS-fed
        f32x4 acc[4];
#pragma unroll
        for (int g = 0; g < 4; ++g) acc[g] = (f32x4){0.f, 0.f, 0.f, 0.f};
        const unsigned short* hrow = &h_lds[lcol * 264 + lkg * 8];
#pragma unroll
        for (int kk = 0; kk < 8; ++kk) {
            const bf16x8 a_ = *(const bf16x8*)(hrow + 32 * kk);
#pragma unroll
            for (int g = 0; g < 4; ++g) {
                const uint4 wv = WL[(4 * kk + lkg) * 256 + g * 64 + 16 * w + lcol];
                acc[g] = __builtin_amdgcn_mfma_f32_16x16x32_bf16(
                    a_, u4_to_b8(wv), acc[g], 0, 0, 0);
            }
        }

        // cell: lane owns (batch = lkg*4+r, col) — all 4 gates in-lane
#pragma unroll
        for (int r = 0; r < 4; ++r) {
            const int batch = lkg * 4 + r;
            const float iv = acc[0][r] + xgv[0][r];
            const float fv = acc[1][r] + xgv[1][r];
            const float gv = acc[2][r] + xgv[2][r];
            const float ov = acc[3][r] + xgv[3][r];
            float c = sig_(fv) * c_reg[r] + sig_(iv) * tanh_(gv);
            c_reg[r] = c;
            const float h = sig_(ov) * tanh_(c);
            out[((long)tt * B_ + batch) * (2 * HD_) + dir * HD_ + col] = h;
            hb[(p ^ 1) * (B_ * HD_) + batch * HD_ + col] = bf16_rtn(h);
        }
        __syncthreads();   // drains h stores (vmcnt(0) before s_barrier)
        if (tid == 0) {
            __threadfence();   // wbl2: h lines -> LLC (R7-proven)
            __hip_atomic_store(&fl[j * 16], (unsigned)(t + 1), __ATOMIC_RELAXED,
                               __HIP_MEMORY_SCOPE_AGENT);
        }
    }
}

// ---------------------------------------------------------------------------
extern "C" void kernel_launch(void* const* d_in, const int* in_sizes, int n_in,
                              void* d_out, int out_size, void* d_ws, size_t ws_size,
                              hipStream_t stream)
{
    const float* src  = (const float*)d_in[1];   // [S][B][H]
    const float* ref  = (const float*)d_in[2];   // [R][B][H]
    const float* Wref = (const float*)d_in[3];   // [H][H]
    const float* bref = (const float*)d_in[4];   // [H]
    const float* Wihf = (const float*)d_in[5];   // [G][DIN]
    const float* Whhf = (const float*)d_in[6];   // [G][HD]
    const float* bihf = (const float*)d_in[7];
    const float* bhhf = (const float*)d_in[8];
    const float* Wihb = (const float*)d_in[9];
    const float* Whhb = (const float*)d_in[10];
    const float* bihb = (const float*)d_in[11];
    const float* bhhb = (const float*)d_in[12];
    float* out = (float*)d_out;                  // [R][B][2*HD]

    float* ws = (float*)d_ws;
    // workspace layout (float offsets):
    float* hs   = ws + 0L;                              // 8388608  [B][S][H]
    float* l    = ws + 8388608L;                        // 8388608  [B][S][R]
    unsigned short* as_bf = (unsigned short*)(ws + 16777216L);  // bf16 [B][S][R]
    unsigned short* refT  = (unsigned short*)(ws + 20971520L);  // bf16 [B][H][R]
    unsigned short* a_rT  = (unsigned short*)(ws + 23068672L);  // bf16 [B][R][S]
    unsigned short* catb  = (unsigned short*)(ws + 27262976L);  // bf16 [B][2H][S]
    unsigned short* binb  = (unsigned short*)(ws + 35651584L);  // bf16 [T*B][DIN]
    unsigned* WB = (unsigned*)(ws + 41943040L);         // 1 MB scan W bf16
    unsigned short* Wib = (unsigned short*)(ws + 42205184L);    // 6 MB W_ih bf16
    unsigned short* hbuf = (unsigned short*)(ws + 43778048L);   // 32 KB h dbuf
    unsigned* flags = (unsigned*)(ws + 43786240L);      // 512 B
    float* xgf = l;                                     // alias (l dead after a_rT)
    float* xgb = ws + 16777216L;                        // alias (dead after step 6)

    // zero h_0 + flags
    hipMemsetAsync(hbuf, 0, 2 * 2 * B_ * HD_ * 2 + 512, stream);

    // 0) one-time weight packs + static ref half of bin
    transpose_w_bf16<<<dim3(4, 32, 2), 256, 0, stream>>>(Whhf, Whhb, WB);
    pack_bf16<<<dim3((G_ * DIN_ / 4 + 255) / 256), 256, 0, stream>>>(
        Wihf, Wib, (long)G_ * DIN_ / 4);
    pack_bf16<<<dim3((G_ * DIN_ / 4 + 255) / 256), 256, 0, stream>>>(
        Wihb, Wib + (long)G_ * DIN_, (long)G_ * DIN_ / 4);
    pack_ref_bin<<<dim3((R_ * B_ * H_ / 4 + 255) / 256), 256, 0, stream>>>(ref, binb);

    // 1) h_s = tanh(src . Wref^T + bref)
    gemm_mk_nk<1, 1><<<dim3(8, 256, 1), 256, 0, stream>>>(
        src, H_, 0, Wref, H_, 0, hs, H_, 0, bref, B_ * S_, H_, H_);

    // 2) l[b] = h_s[b] . h_r[b]^T
    gemm_mk_nk<0, 0><<<dim3(8, 16, B_), 256, 0, stream>>>(
        hs, H_, (long)S_ * H_, ref, (long)B_ * H_, H_, l, R_, (long)S_ * R_,
        nullptr, S_, R_, H_);

    // 3) softmaxes: a_s -> bf16; a_r in place (fp32)
    softmax_cols<<<dim3(R_ / 128, B_), 512, 0, stream>>>(l, as_bf);
    softmax_rows<<<(B_ * S_) / 4, 256, 0, stream>>>(l);

    // 3b) bf16 transposes for the MFMA attention GEMMs
    transpose_ref<<<dim3(R_ / 32, H_ / 32, B_), dim3(32, 8), 0, stream>>>(ref, refT);
    transpose_arT<<<dim3(S_ / 32, R_ / 32, B_), dim3(32, 8), 0, stream>>>(l, a_rT);

    // 4) cat_bf rows 0..511 = h_s^T (bf16)
    transpose_hs<<<dim3(S_ / 32, H_ / 32, B_), dim3(32, 8), 0, stream>>>(hs, catb);

    // 5) cat_bf rows 512..1023: c_s[b,h,s] = sum_r refT[b,h,r]*a_s[b,s,r]  (MFMA)
    gemm56<0><<<dim3(S_ / 64, H_ / 64, B_), 256, 0, stream>>>(
        refT, (long)H_ * R_, R_, as_bf, (long)S_ * R_, R_,
        catb + (long)H_ * S_, (long)2 * H_ * S_, S_, R_);

    // 6) c_r[b,r,m] = sum_s cat_bf[b,m,s]*a_rT[b,r,s]  written DIRECTLY into
    //    bin's dynamic half (bf16, row = r*B+b): eliminates build_bin.
    gemm56<1><<<dim3(R_ / 64, 2 * H_ / 64, B_), 256, 0, stream>>>(
        catb, (long)2 * H_ * S_, S_, a_rT, (long)R_ * S_, S_,
        binb, (long)DIN_, (long)B_ * DIN_, S_);

    // 8) xg = bin . W_ih^T + b_ih + b_hh  via MFMA
    gemm_xg_mfma<<<dim3(G_ / 64, R_ * B_ / 64, 2), 256, 0, stream>>>(
        binb, Wib, bihf, bhhf, bihb, bhhb, xgf, xgb);

    // 9) bi-LSTM scan: 4 blocks/dir, W LDS-resident, R18 fence-flag sync
    lstm_scan_s<<<dim3(2 * NBD), dim3(256), 0, stream>>>(
        xgf, xgb, (const uint4*)WB, hbuf, flags, out);
}